// Round 11
// baseline (456.233 us; speedup 1.0000x reference)
//
#include <hip/hip_runtime.h>
#include <hip/hip_bf16.h>
#include <math.h>

// RG-LRU block: GEMM1 -> depthwise causal conv -> GEMM2 -> chunked linear scan -> GEMM3
// GEMMs locked (gemm8x 256x256 8-phase, gemm128 for GEMM3 — r10 baseline).
// This round: 8-wide tail (conv/scan1/scan3 ushort8) at proven NCHUNK=64 geometry,
// scan2 batched-load latency fix.

#define HIDC 2048
#define DIMC 1024
#define BBC 4
#define TTC 2048
#define BTC (BBC*TTC)      // 8192 rows
#define NCHUNK 64
#define CLEN 32            // TTC / NCHUNK

typedef __attribute__((ext_vector_type(8))) short bfx8;
typedef __attribute__((ext_vector_type(4))) float f32x4;

__device__ __forceinline__ unsigned short f2bf(float f) {
    return __builtin_bit_cast(unsigned short, __float2bfloat16(f));
}
__device__ __forceinline__ float bf2f(unsigned short u) {
    union { unsigned int i; float f; } v; v.i = ((unsigned)u) << 16; return v.f;
}
__device__ __forceinline__ float bf_at(const uint4& v, int j) {
    const unsigned w = ((const unsigned*)&v)[j >> 1];
    return bf2f((unsigned short)((j & 1) ? (w >> 16) : (w & 0xffff)));
}
__device__ __forceinline__ uint4 pack8(const float* f) {
    uint4 r;
    r.x = (unsigned)f2bf(f[0]) | ((unsigned)f2bf(f[1]) << 16);
    r.y = (unsigned)f2bf(f[2]) | ((unsigned)f2bf(f[3]) << 16);
    r.z = (unsigned)f2bf(f[4]) | ((unsigned)f2bf(f[5]) << 16);
    r.w = (unsigned)f2bf(f[6]) | ((unsigned)f2bf(f[7]) << 16);
    return r;
}
__device__ __forceinline__ float gelu_exact(float x) {
    return 0.5f * x * (1.0f + erff(x * 0.70710678118654752f));
}

typedef const unsigned int __attribute__((address_space(1)))* gas_ptr;
typedef unsigned int __attribute__((address_space(3)))* las_ptr;
__device__ __forceinline__ void gload_lds16(const void* g, void* l) {
    __builtin_amdgcn_global_load_lds((gas_ptr)g, (las_ptr)l, 16, 0, 0);
}

// Stage one 128-row x 64-col bf16 half-tile with 8 waves (2 gloads/wave).
__device__ __forceinline__ void stage_half(
    const unsigned short* __restrict__ gsrc,
    int ld, unsigned short* ldsdst, int wave)
{
    #pragma unroll
    for (int j = 0; j < 2; ++j) {
        const int r0 = (wave * 2 + j) * 8;
        gload_lds16(gsrc + (size_t)r0 * ld, ldsdst + r0 * 64);
    }
}
// Stage one 128-row x 64-col bf16 tile with 4 waves (4 gloads/wave).
__device__ __forceinline__ void stage_q(
    const unsigned short* __restrict__ gsrc,
    int ld, unsigned short* ldsdst, int wave)
{
    #pragma unroll
    for (int j = 0; j < 4; ++j) {
        const int r0 = (wave * 4 + j) * 8;
        gload_lds16(gsrc + (size_t)r0 * ld, ldsdst + r0 * 64);
    }
}

#define SBAR()  __builtin_amdgcn_sched_barrier(0)
#define BAR()   do { SBAR(); __builtin_amdgcn_s_barrier(); SBAR(); } while (0)

// ===========================================================================
// gemm8x: 256x256 tile, BK=64, 8 waves (2Mx4N), 8 phases per 2 K-tiles.
// (r10 locked baseline — 138 us / 43% MfmaUtil on GEMM2.)
// ===========================================================================
template<typename TC, int BIAS>
__global__ __launch_bounds__(512, 2) void gemm8x(
    const unsigned short* __restrict__ A, int lda,
    const unsigned short* __restrict__ Bm, int ldb,
    TC* __restrict__ C, int ldc,
    const float* __restrict__ bias, int K, int gridN, int q8)
{
    __shared__ __align__(16) unsigned short lds[2][2][256 * 64]; // [buf][A/B]

    const int tid  = threadIdx.x;
    const int lin  = blockIdx.x;
    const int swz  = (lin & 7) * q8 + (lin >> 3);      // XCD swizzle (nwg%8==0)
    const int bm   = swz / gridN, bn = swz % gridN;

    const int wave = tid >> 6, lane = tid & 63;
    const int wm   = wave >> 2, wn = wave & 3;
    const int lrow = lane & 15, lq = lane >> 4;

    const int key = (lrow & 7) << 3;
    const int e0  = (lq << 3) ^ key;
    const int e1  = e0 ^ 32;
    const int aRow = (wm * 64 + lrow) * 64;
    const int bRow = (wn * 32 + lrow) * 64;

    const int grow = lane >> 3;
    const int gswz = ((lane & 7) ^ (grow & 7)) << 3;
    const unsigned short* aS = A  + (size_t)(bm * 256 + grow) * lda + gswz;
    const unsigned short* bS = Bm + (size_t)(bn * 256 + grow) * ldb + gswz;

    f32x4 acc[8][4];
    #pragma unroll
    for (int i = 0; i < 8; ++i)
        #pragma unroll
        for (int n = 0; n < 4; ++n)
            acc[i][n] = (f32x4){0.f, 0.f, 0.f, 0.f};

    bfx8 areg[4][2], b0r[2][2], b1r[2][2];
    const int NT = K >> 6;   // even (K = 1024 or 2048)

    auto rdA = [&](const unsigned short* Ah) {
        #pragma unroll
        for (int i = 0; i < 4; ++i) {
            areg[i][0] = *(const bfx8*)(Ah + aRow + i * 1024 + e0);
            areg[i][1] = *(const bfx8*)(Ah + aRow + i * 1024 + e1);
        }
    };
    auto rdB = [&](const unsigned short* Bh, bfx8 (&br)[2][2]) {
        #pragma unroll
        for (int n = 0; n < 2; ++n) {
            br[n][0] = *(const bfx8*)(Bh + bRow + n * 1024 + e0);
            br[n][1] = *(const bfx8*)(Bh + bRow + n * 1024 + e1);
        }
    };
    auto mm = [&](int io, int no, bfx8 (&br)[2][2]) {
        __builtin_amdgcn_s_setprio(1);
        #pragma unroll
        for (int i = 0; i < 4; ++i)
            #pragma unroll
            for (int n = 0; n < 2; ++n)
                #pragma unroll
                for (int kk = 0; kk < 2; ++kk)
                    acc[io + i][no + n] = __builtin_amdgcn_mfma_f32_16x16x32_bf16(
                        areg[i][kk], br[n][kk], acc[io + i][no + n], 0, 0, 0);
        __builtin_amdgcn_s_setprio(0);
    };

#define WAITS() do { \
        if (deep) { asm volatile("s_waitcnt vmcnt(6)" ::: "memory"); } \
        else      { asm volatile("s_waitcnt vmcnt(0)" ::: "memory"); } \
        BAR(); \
        asm volatile("s_waitcnt lgkmcnt(0)" ::: "memory"); \
        SBAR(); \
    } while (0)

    // prologue
    stage_half(aS,                       lda, &lds[0][0][0],    wave);
    stage_half(bS,                       ldb, &lds[0][1][0],    wave);
    stage_half(bS + (size_t)128 * ldb,   ldb, &lds[0][1][8192], wave);
    stage_half(aS + (size_t)128 * lda,   lda, &lds[0][0][8192], wave);
    stage_half(aS + 64,                  lda, &lds[1][0][0],    wave);
    stage_half(bS + 64,                  ldb, &lds[1][1][0],    wave);
    asm volatile("s_waitcnt vmcnt(8)" ::: "memory");
    BAR();

    for (int T = 0; T < NT; T += 2) {
        const bool deep = (T + 2 < NT);
        const int k1 = (T + 1) << 6, k2 = (T + 2) << 6, k3 = (T + 3) << 6;

        rdA(&lds[0][0][0]); rdB(&lds[0][1][0], b0r);
        stage_half(bS + (size_t)128 * ldb + k1, ldb, &lds[1][1][8192], wave);
        WAITS(); mm(0, 0, b0r); BAR();

        rdB(&lds[0][1][8192], b1r);
        stage_half(aS + (size_t)128 * lda + k1, lda, &lds[1][0][8192], wave);
        WAITS(); mm(0, 2, b1r); BAR();

        rdA(&lds[0][0][8192]);
        if (deep) stage_half(aS + k2, lda, &lds[0][0][0], wave);
        WAITS(); mm(4, 2, b1r); BAR();

        if (deep) stage_half(bS + k2, ldb, &lds[0][1][0], wave);
        WAITS(); mm(4, 0, b0r); BAR();

        rdA(&lds[1][0][0]); rdB(&lds[1][1][0], b0r);
        if (deep) stage_half(bS + (size_t)128 * ldb + k2, ldb, &lds[0][1][8192], wave);
        WAITS(); mm(0, 0, b0r); BAR();

        rdB(&lds[1][1][8192], b1r);
        if (deep) stage_half(aS + (size_t)128 * lda + k2, lda, &lds[0][0][8192], wave);
        WAITS(); mm(0, 2, b1r); BAR();

        rdA(&lds[1][0][8192]);
        if (deep) stage_half(aS + k3, lda, &lds[1][0][0], wave);
        WAITS(); mm(4, 2, b1r); BAR();

        if (deep) stage_half(bS + k3, ldb, &lds[1][1][0], wave);
        WAITS(); mm(4, 0, b0r); BAR();
    }
#undef WAITS

    #pragma unroll
    for (int ai = 0; ai < 8; ++ai) {
        const int a = ai >> 2, i = ai & 3;
        const int row0 = bm * 256 + a * 128 + wm * 64 + i * 16 + lq * 4;
        #pragma unroll
        for (int c = 0; c < 4; ++c) {
            const int col = bn * 256 + (c >> 1) * 128 + wn * 32 + (c & 1) * 16 + lrow;
            float bv = 0.f;
            if (BIAS) bv = bias[col];
            #pragma unroll
            for (int r = 0; r < 4; ++r) {
                const float v = acc[ai][c][r] + bv;
                if constexpr (sizeof(TC) == 2)
                    C[(size_t)(row0 + r) * ldc + col] = (TC)f2bf(v);
                else
                    C[(size_t)(row0 + r) * ldc + col] = (TC)v;
            }
        }
    }
}

// ===========================================================================
// gemm128: 128x128 tile @ 2 blocks/CU (r9/r10 proven, GEMM3)
// ===========================================================================
template<typename TC>
__global__ __launch_bounds__(256, 2) void gemm128(
    const unsigned short* __restrict__ A, int lda,
    const unsigned short* __restrict__ Bm, int ldb,
    TC* __restrict__ C, int ldc, int K, int gridN, int q8)
{
    __shared__ __align__(16) unsigned short lds[2][2][128 * 64]; // 64 KiB

    const int tid  = threadIdx.x;
    const int lin  = blockIdx.x;
    const int swz  = (lin & 7) * q8 + (lin >> 3);
    const int bm   = swz / gridN, bn = swz % gridN;

    const int wave = tid >> 6, lane = tid & 63;
    const int wm   = wave >> 1, wn = wave & 1;
    const int lrow = lane & 15, lq = lane >> 4;

    const int key = (lrow & 7) << 3;
    const int e0  = (lq << 3) ^ key;
    const int e1  = e0 ^ 32;
    const int aRow = (wm * 64 + lrow) * 64;
    const int bRow = (wn * 64 + lrow) * 64;

    const int grow = lane >> 3;
    const int gswz = ((lane & 7) ^ (grow & 7)) << 3;
    const unsigned short* aS = A  + (size_t)(bm * 128 + grow) * lda + gswz;
    const unsigned short* bS = Bm + (size_t)(bn * 128 + grow) * ldb + gswz;

    f32x4 acc[4][4];
    #pragma unroll
    for (int i = 0; i < 4; ++i)
        #pragma unroll
        for (int n = 0; n < 4; ++n)
            acc[i][n] = (f32x4){0.f, 0.f, 0.f, 0.f};

    bfx8 areg[4][2], breg[4][2];
    const int NT = K >> 6;

    stage_q(aS, lda, &lds[0][0][0], wave);
    stage_q(bS, ldb, &lds[0][1][0], wave);

    for (int t = 0; t < NT; ++t) {
        const int cur = t & 1, nxt = cur ^ 1;
        const unsigned short* Ac = lds[cur][0];
        const unsigned short* Bc = lds[cur][1];
        const bool hn = (t + 1 < NT);
        const int k1 = (t + 1) << 6;

        if (hn) {
            stage_q(aS + k1, lda, &lds[nxt][0][0], wave);
            stage_q(bS + k1, ldb, &lds[nxt][1][0], wave);
            asm volatile("s_waitcnt vmcnt(8)" ::: "memory");
        } else {
            asm volatile("s_waitcnt vmcnt(0)" ::: "memory");
        }
        BAR();

        #pragma unroll
        for (int i = 0; i < 4; ++i) {
            areg[i][0] = *(const bfx8*)(Ac + aRow + i * 1024 + e0);
            areg[i][1] = *(const bfx8*)(Ac + aRow + i * 1024 + e1);
        }
        #pragma unroll
        for (int n = 0; n < 4; ++n) {
            breg[n][0] = *(const bfx8*)(Bc + bRow + n * 1024 + e0);
            breg[n][1] = *(const bfx8*)(Bc + bRow + n * 1024 + e1);
        }
        #pragma unroll
        for (int i = 0; i < 4; ++i)
            #pragma unroll
            for (int n = 0; n < 4; ++n)
                #pragma unroll
                for (int kk = 0; kk < 2; ++kk)
                    acc[i][n] = __builtin_amdgcn_mfma_f32_16x16x32_bf16(areg[i][kk], breg[n][kk], acc[i][n], 0, 0, 0);
        BAR();
    }

    #pragma unroll
    for (int i = 0; i < 4; ++i) {
        const int row0 = bm * 128 + wm * 64 + i * 16 + lq * 4;
        #pragma unroll
        for (int n = 0; n < 4; ++n) {
            const int col = bn * 128 + wn * 64 + n * 16 + lrow;
            #pragma unroll
            for (int r = 0; r < 4; ++r) {
                const float v = acc[i][n][r];
                if constexpr (sizeof(TC) == 2)
                    C[(size_t)(row0 + r) * ldc + col] = (TC)f2bf(v);
                else
                    C[(size_t)(row0 + r) * ldc + col] = (TC)v;
            }
        }
    }
}

// ===========================================================================
// Fallback 128x128 GEMM for small workspace (r3 proven)
// ===========================================================================
template<typename T>
__device__ __forceinline__ void stage_op(const T* __restrict__ base, int ld, int k0,
                                         unsigned short* lds_, int tid)
{
    if constexpr (sizeof(T) == 2) {
        const int wave = tid >> 6, lane = tid & 63;
        const int grow = lane >> 3;
        const int gcol = (lane & 7) << 3;
        #pragma unroll
        for (int j = 0; j < 4; ++j) {
            const int r0 = wave * 32 + j * 8;
            gload_lds16((const unsigned short*)base + (size_t)(r0 + grow) * ld + k0 + gcol,
                        &lds_[r0 * 64]);
        }
    } else {
        const int srow = tid >> 4, scol = (tid & 15) << 2;
        #pragma unroll
        for (int p = 0; p < 8; ++p) {
            const int r = p * 16 + srow;
            const float4 v = *(const float4*)((const float*)base + (size_t)r * ld + k0 + scol);
            uint2 w;
            w.x = (unsigned)f2bf(v.x) | ((unsigned)f2bf(v.y) << 16);
            w.y = (unsigned)f2bf(v.z) | ((unsigned)f2bf(v.w) << 16);
            *(uint2*)&lds_[r * 64 + scol] = w;
        }
    }
}

template<typename TA, typename TB, typename TC, int BIAS>
__global__ __launch_bounds__(256) void gemm_bt(
    const TA* __restrict__ A, int lda,
    const TB* __restrict__ Bm, int ldb,
    TC* __restrict__ C, int ldc,
    const float* __restrict__ bias, int K)
{
    __shared__ __align__(16) unsigned short As[128 * 64];
    __shared__ __align__(16) unsigned short Bs[128 * 64];

    const int tid  = threadIdx.x;
    const int bm   = blockIdx.y, bn = blockIdx.x;
    const int wave = tid >> 6,  lane = tid & 63;
    const int wm   = wave >> 1, wn = wave & 1;
    const int lrow = lane & 15, lq = lane >> 4;

    f32x4 acc[4][4];
    #pragma unroll
    for (int i = 0; i < 4; ++i)
        #pragma unroll
        for (int j = 0; j < 4; ++j)
            acc[i][j] = (f32x4){0.f, 0.f, 0.f, 0.f};

    const TA* Abase = A  + (size_t)(bm * 128) * lda;
    const TB* Bbase = Bm + (size_t)(bn * 128) * ldb;

    for (int k0 = 0; k0 < K; k0 += 64) {
        stage_op<TA>(Abase, lda, k0, As, tid);
        stage_op<TB>(Bbase, ldb, k0, Bs, tid);
        __syncthreads();
        #pragma unroll
        for (int kk = 0; kk < 2; ++kk) {
            bfx8 af[4], bfr[4];
            const int kb = kk * 32 + lq * 8;
            #pragma unroll
            for (int m = 0; m < 4; ++m)
                af[m] = *(const bfx8*)&As[(wm * 64 + m * 16 + lrow) * 64 + kb];
            #pragma unroll
            for (int n = 0; n < 4; ++n)
                bfr[n] = *(const bfx8*)&Bs[(wn * 64 + n * 16 + lrow) * 64 + kb];
            #pragma unroll
            for (int m = 0; m < 4; ++m)
                #pragma unroll
                for (int n = 0; n < 4; ++n)
                    acc[m][n] = __builtin_amdgcn_mfma_f32_16x16x32_bf16(af[m], bfr[n], acc[m][n], 0, 0, 0);
        }
        __syncthreads();
    }

    #pragma unroll
    for (int m = 0; m < 4; ++m) {
        #pragma unroll
        for (int n = 0; n < 4; ++n) {
            const int row0 = bm * 128 + wm * 64 + m * 16 + lq * 4;
            const int col  = bn * 128 + wn * 64 + n * 16 + lrow;
            float bv = 0.f;
            if (BIAS) bv = bias[col];
            #pragma unroll
            for (int r = 0; r < 4; ++r) {
                const float v = acc[m][n][r] + bv;
                if constexpr (sizeof(TC) == 2)
                    C[(size_t)(row0 + r) * ldc + col] = (TC)f2bf(v);
                else
                    C[(size_t)(row0 + r) * ldc + col] = (TC)v;
            }
        }
    }
}

// ---------------------------------------------------------------------------
// fused fp32->bf16 convert of 4 segments (x, W_in, W_g, W_out), 8 elems/thread
// ---------------------------------------------------------------------------
__global__ __launch_bounds__(256) void cvt_all(
    const float* __restrict__ s0, unsigned short* __restrict__ d0, int n0,
    const float* __restrict__ s1, unsigned short* __restrict__ d1, int n1,
    const float* __restrict__ s2, unsigned short* __restrict__ d2, int n2,
    const float* __restrict__ s3, unsigned short* __restrict__ d3, int n3)
{
    int i = blockIdx.x * 256 + threadIdx.x;
    const float* src; unsigned short* dst;
    if (i < n0)                { src = s0; dst = d0; }
    else if ((i -= n0) < n1)   { src = s1; dst = d1; }
    else if ((i -= n1) < n2)   { src = s2; dst = d2; }
    else if ((i -= n2) < n3)   { src = s3; dst = d3; }
    else return;
    const float4 a = ((const float4*)src)[i * 2];
    const float4 b = ((const float4*)src)[i * 2 + 1];
    uint4 w;
    w.x = (unsigned)f2bf(a.x) | ((unsigned)f2bf(a.y) << 16);
    w.y = (unsigned)f2bf(a.z) | ((unsigned)f2bf(a.w) << 16);
    w.z = (unsigned)f2bf(b.x) | ((unsigned)f2bf(b.y) << 16);
    w.w = (unsigned)f2bf(b.z) | ((unsigned)f2bf(b.w) << 16);
    ((uint4*)dst)[i] = w;
}

// ---------------------------------------------------------------------------
// causal depthwise conv, K=4: 8 h per thread (ushort8 loads/stores)
// ---------------------------------------------------------------------------
__global__ __launch_bounds__(256) void conv_k(
    const unsigned short* __restrict__ gi, const float* __restrict__ w,
    const float* __restrict__ cb, unsigned short* __restrict__ xc)
{
    const int idx = blockIdx.x * 256 + threadIdx.x;   // BTC*256
    const int h64 = idx & 255, bt = idx >> 8;
    const int h = h64 << 3;
    const int t = bt & (TTC - 1);

    float acc[8];
    #pragma unroll
    for (int j = 0; j < 8; j += 4) {
        const float4 c4 = *(const float4*)&cb[h + j];
        acc[j] = c4.x; acc[j + 1] = c4.y; acc[j + 2] = c4.z; acc[j + 3] = c4.w;
    }
    float4 wv[8];
    #pragma unroll
    for (int j = 0; j < 8; ++j) wv[j] = *(const float4*)&w[(h + j) * 4];

    #pragma unroll
    for (int k = 0; k < 4; ++k) {
        if (t - 3 + k >= 0) {
            const uint4 v = *(const uint4*)&gi[(size_t)(bt - 3 + k) * 4096 + 2048 + h];
            #pragma unroll
            for (int j = 0; j < 8; ++j)
                acc[j] += ((const float*)&wv[j])[k] * bf_at(v, j);
        }
    }
    *(uint4*)&xc[(size_t)bt * 2048 + h] = pack8(acc);
}

// ---------------------------------------------------------------------------
// scan pass 1: per (b,chunk,8h) local scan of 32 steps -> chunk summaries
// (pA_end, hl_end). NCHUNK=64 (proven geometry), 8h/thread uint4 loads.
// ---------------------------------------------------------------------------
__global__ __launch_bounds__(256) void scan1(
    const unsigned short* __restrict__ g, const unsigned short* __restrict__ xc,
    const float* __restrict__ fb, float2* __restrict__ sums)
{
    const int idx = blockIdx.x * 256 + threadIdx.x;   // 4*64*256 = 65536
    const int h = (idx & 255) << 3;
    const int c = (idx >> 8) & (NCHUNK - 1);
    const int b = idx >> 14;

    float c1[8];
    #pragma unroll
    for (int j = 0; j < 8; ++j) c1[j] = -8.0f * log1pf(expf(fb[h + j]));

    float pA[8], hl[8];
    #pragma unroll
    for (int j = 0; j < 8; ++j) { pA[j] = 1.f; hl[j] = 0.f; }

    const int row0 = b * TTC + c * CLEN;
    for (int tl = 0; tl < CLEN; ++tl) {
        const size_t row = (size_t)(row0 + tl);
        const uint4 gf = *(const uint4*)&g[row * 4096 + h];
        const uint4 gn = *(const uint4*)&g[row * 4096 + 2048 + h];
        const uint4 xv = *(const uint4*)&xc[row * 2048 + h];
        #pragma unroll
        for (int j = 0; j < 8; ++j) {
            const float sf = 1.f / (1.f + expf(-bf_at(gf, j)));
            const float a  = expf(c1[j] * sf);
            const float be = sqrtf(1.f - a * a + 1e-6f);
            const float si = 1.f / (1.f + expf(-bf_at(gn, j)));
            hl[j] = a * hl[j] + be * si * bf_at(xv, j);
            pA[j] *= a;
        }
    }
    float4* sp = (float4*)&sums[(size_t)(c * BBC + b) * HIDC + h];
    sp[0] = (float4){pA[0], hl[0], pA[1], hl[1]};
    sp[1] = (float4){pA[2], hl[2], pA[3], hl[3]};
    sp[2] = (float4){pA[4], hl[4], pA[5], hl[5]};
    sp[3] = (float4){pA[6], hl[6], pA[7], hl[7]};
}

// ---------------------------------------------------------------------------
// scan pass 2: per (b,h) combine 64 summaries -> carry per chunk.
// Batched loads (8 in flight) cut the dependent-latency chain 8x.
// ---------------------------------------------------------------------------
__global__ __launch_bounds__(256) void scan2(
    const float2* __restrict__ sums, float* __restrict__ carry)
{
    const int idx = blockIdx.x * 256 + threadIdx.x;   // BBC*HIDC = 8192
    const int h = idx & (HIDC - 1), b = idx >> 11;
    float cy = 0.f;
    for (int c0 = 0; c0 < NCHUNK; c0 += 8) {
        float2 s[8];
        #pragma unroll
        for (int j = 0; j < 8; ++j)
            s[j] = sums[(size_t)((c0 + j) * BBC + b) * HIDC + h];
        #pragma unroll
        for (int j = 0; j < 8; ++j) {
            carry[(size_t)((c0 + j) * BBC + b) * HIDC + h] = cy;
            cy = s[j].y + s[j].x * cy;
        }
    }
}

// ---------------------------------------------------------------------------
// scan pass 3: rerun local scan seeded with carry; u = gelu(gate)*h written
// in-place over gi's gate half. 8h/thread uint4 loads/stores.
// ---------------------------------------------------------------------------
__global__ __launch_bounds__(256) void scan3(
    unsigned short* __restrict__ gi, const unsigned short* __restrict__ g,
    const unsigned short* __restrict__ xc, const float* __restrict__ fb,
    const float* __restrict__ carry)
{
    const int idx = blockIdx.x * 256 + threadIdx.x;   // 65536
    const int h = (idx & 255) << 3;
    const int c = (idx >> 8) & (NCHUNK - 1);
    const int b = idx >> 14;

    float c1[8];
    #pragma unroll
    for (int j = 0; j < 8; ++j) c1[j] = -8.0f * log1pf(expf(fb[h + j]));

    float hh[8];
    {
        const float4* cp = (const float4*)&carry[(size_t)(c * BBC + b) * HIDC + h];
        const float4 c0v = cp[0], c1v = cp[1];
        hh[0] = c0v.x; hh[1] = c0v.y; hh[2] = c0v.z; hh[3] = c0v.w;
        hh[4] = c1v.x; hh[5] = c1v.y; hh[6] = c1v.z; hh[7] = c1v.w;
    }

    const int row0 = b * TTC + c * CLEN;
    for (int tl = 0; tl < CLEN; ++tl) {
        const size_t row = (size_t)(row0 + tl);
        const uint4 gf = *(const uint4*)&g[row * 4096 + h];
        const uint4 gn = *(const uint4*)&g[row * 4096 + 2048 + h];
        const uint4 xv = *(const uint4*)&xc[row * 2048 + h];
        const uint4 gt = *(const uint4*)&gi[row * 4096 + h];
        float u[8];
        #pragma unroll
        for (int j = 0; j < 8; ++j) {
            const float sf = 1.f / (1.f + expf(-bf_at(gf, j)));
            const float a  = expf(c1[j] * sf);
            const float be = sqrtf(1.f - a * a + 1e-6f);
            const float si = 1.f / (1.f + expf(-bf_at(gn, j)));
            hh[j] = a * hh[j] + be * si * bf_at(xv, j);
            u[j] = gelu_exact(bf_at(gt, j)) * hh[j];
        }
        *(uint4*)&gi[row * 4096 + h] = pack8(u);
    }
}

// ---------------------------------------------------------------------------
extern "C" void kernel_launch(void* const* d_in, const int* in_sizes, int n_in,
                              void* d_out, int out_size, void* d_ws, size_t ws_size,
                              hipStream_t stream)
{
    const float* x     = (const float*)d_in[0];
    const float* W_in  = (const float*)d_in[1];
    const float* cw    = (const float*)d_in[2];
    const float* cb    = (const float*)d_in[3];
    const float* W_g   = (const float*)d_in[4];
    const float* b_g   = (const float*)d_in[5];
    const float* fb    = (const float*)d_in[6];
    const float* W_out = (const float*)d_in[7];
    float* out = (float*)d_out;

    const size_t n_gi  = (size_t)BTC * 4096;            // bf16
    const size_t n_g   = (size_t)BTC * 4096;            // bf16
    const size_t n_xc  = (size_t)BTC * 2048;            // bf16
    const size_t n_sum = (size_t)NCHUNK * BBC * HIDC;   // float2 / float
    const size_t nX    = (size_t)BTC * DIMC;
    const size_t nWin  = (size_t)4096 * 1024;
    const size_t nWg   = (size_t)4096 * 2048;
    const size_t nWout = (size_t)1024 * 2048;

    const size_t need_base = (n_gi + n_g + n_xc) * 2 + n_sum * 12;     // 166 MiB
    const size_t need_full = need_base + (nWg + nWout) * 2;            // 186 MiB
    if (ws_size < need_base) return;
    const bool use8 = (ws_size >= need_full);

    unsigned short* gi = (unsigned short*)d_ws;
    unsigned short* g  = gi + n_gi;
    unsigned short* xc = g + n_g;
    float2* sums  = (float2*)(xc + n_xc);
    float*  carry = (float*)(sums + n_sum);
    unsigned short* wg_bf   = (unsigned short*)(carry + n_sum);
    unsigned short* wout_bf = wg_bf + nWg;
    unsigned short* x_bf   = g;            // aliases g (dead until GEMM2)
    unsigned short* win_bf = g + nX;

    if (use8) {
        const int n0 = (int)(nX / 8), n1 = (int)(nWin / 8),
                  n2 = (int)(nWg / 8), n3 = (int)(nWout / 8);
        cvt_all<<<(n0 + n1 + n2 + n3 + 255) / 256, 256, 0, stream>>>(
            x, x_bf, n0, W_in, win_bf, n1, W_g, wg_bf, n2, W_out, wout_bf, n3);

        // GEMM1: gi = x @ W_in^T        M=8192 N=4096 K=1024   nwg=512
        gemm8x<unsigned short, 0><<<512, 512, 0, stream>>>(
            x_bf, DIMC, win_bf, DIMC, gi, 4096, nullptr, DIMC, 16, 64);

        conv_k<<<(BTC * 256) / 256, 256, 0, stream>>>(gi, cw, cb, xc);

        // GEMM2: g = xc @ W_g^T + b_g   M=8192 N=4096 K=2048   nwg=512
        gemm8x<unsigned short, 1><<<512, 512, 0, stream>>>(
            xc, HIDC, wg_bf, HIDC, g, 4096, b_g, HIDC, 16, 64);

        scan1<<<(BBC * NCHUNK * 256) / 256, 256, 0, stream>>>(g, xc, fb, sums);
        scan2<<<(BBC * HIDC) / 256, 256, 0, stream>>>(sums, carry);
        scan3<<<(BBC * NCHUNK * 256) / 256, 256, 0, stream>>>(gi, g, xc, fb, carry);

        // GEMM3: out = u @ W_out^T      M=8192 N=1024 K=2048   gemm128 512 blocks
        gemm128<float><<<512, 256, 0, stream>>>(
            gi, 4096, wout_bf, HIDC, out, DIMC, HIDC, 8, 64);
    } else {
        gemm_bt<float, float, unsigned short, 0>
            <<<dim3(4096 / 128, BTC / 128), 256, 0, stream>>>(
            x, DIMC, W_in, DIMC, gi, 4096, nullptr, DIMC);
        conv_k<<<(BTC * 256) / 256, 256, 0, stream>>>(gi, cw, cb, xc);
        gemm_bt<unsigned short, float, unsigned short, 1>
            <<<dim3(4096 / 128, BTC / 128), 256, 0, stream>>>(
            xc, HIDC, W_g, HIDC, g, 4096, b_g, HIDC);
        scan1<<<(BBC * NCHUNK * 256) / 256, 256, 0, stream>>>(g, xc, fb, sums);
        scan2<<<(BBC * HIDC) / 256, 256, 0, stream>>>(sums, carry);
        scan3<<<(BBC * NCHUNK * 256) / 256, 256, 0, stream>>>(gi, g, xc, fb, carry);
        gemm_bt<unsigned short, float, float, 0>
            <<<dim3(DIMC / 128, BTC / 128), 256, 0, stream>>>(
            gi, 4096, W_out, HIDC, out, DIMC, nullptr, HIDC);
    }
}

// Round 12
// 401.269 us; speedup vs baseline: 1.1370x; 1.1370x over previous
//
#include <hip/hip_runtime.h>
#include <hip/hip_bf16.h>
#include <math.h>

// RG-LRU block: GEMM1 -> depthwise causal conv -> GEMM2 -> chunked linear scan -> GEMM3
// r10 best (402.5us) restored: gemm8x 256x256 8-phase (GEMM1/2), gemm128 2-blk/CU (GEMM3),
// scalar high-TLP tail (conv 4h/thread, scan1/scan3 1h/thread, NCHUNK=64), fused cvt.
// Only r11 piece kept: scan2 batched summary loads (latency-chain fix, geometry unchanged).

#define HIDC 2048
#define DIMC 1024
#define BBC 4
#define TTC 2048
#define BTC (BBC*TTC)      // 8192 rows
#define NCHUNK 64
#define CLEN 32            // TTC / NCHUNK

typedef __attribute__((ext_vector_type(8))) short bfx8;
typedef __attribute__((ext_vector_type(4))) float f32x4;

__device__ __forceinline__ unsigned short f2bf(float f) {
    return __builtin_bit_cast(unsigned short, __float2bfloat16(f));
}
__device__ __forceinline__ float bf2f(unsigned short u) {
    union { unsigned int i; float f; } v; v.i = ((unsigned)u) << 16; return v.f;
}
__device__ __forceinline__ float gelu_exact(float x) {
    return 0.5f * x * (1.0f + erff(x * 0.70710678118654752f));
}

typedef const unsigned int __attribute__((address_space(1)))* gas_ptr;
typedef unsigned int __attribute__((address_space(3)))* las_ptr;
__device__ __forceinline__ void gload_lds16(const void* g, void* l) {
    __builtin_amdgcn_global_load_lds((gas_ptr)g, (las_ptr)l, 16, 0, 0);
}

// Stage one 128-row x 64-col bf16 half-tile with 8 waves (2 gloads/wave).
__device__ __forceinline__ void stage_half(
    const unsigned short* __restrict__ gsrc,
    int ld, unsigned short* ldsdst, int wave)
{
    #pragma unroll
    for (int j = 0; j < 2; ++j) {
        const int r0 = (wave * 2 + j) * 8;
        gload_lds16(gsrc + (size_t)r0 * ld, ldsdst + r0 * 64);
    }
}
// Stage one 128-row x 64-col bf16 tile with 4 waves (4 gloads/wave).
__device__ __forceinline__ void stage_q(
    const unsigned short* __restrict__ gsrc,
    int ld, unsigned short* ldsdst, int wave)
{
    #pragma unroll
    for (int j = 0; j < 4; ++j) {
        const int r0 = (wave * 4 + j) * 8;
        gload_lds16(gsrc + (size_t)r0 * ld, ldsdst + r0 * 64);
    }
}

#define SBAR()  __builtin_amdgcn_sched_barrier(0)
#define BAR()   do { SBAR(); __builtin_amdgcn_s_barrier(); SBAR(); } while (0)

// ===========================================================================
// gemm8x: 256x256 tile, BK=64, 8 waves (2Mx4N), 8 phases per 2 K-tiles.
// (locked baseline — 138 us / 43% MfmaUtil on GEMM2; six-variant plateau.)
// ===========================================================================
template<typename TC, int BIAS>
__global__ __launch_bounds__(512, 2) void gemm8x(
    const unsigned short* __restrict__ A, int lda,
    const unsigned short* __restrict__ Bm, int ldb,
    TC* __restrict__ C, int ldc,
    const float* __restrict__ bias, int K, int gridN, int q8)
{
    __shared__ __align__(16) unsigned short lds[2][2][256 * 64]; // [buf][A/B]

    const int tid  = threadIdx.x;
    const int lin  = blockIdx.x;
    const int swz  = (lin & 7) * q8 + (lin >> 3);      // XCD swizzle (nwg%8==0)
    const int bm   = swz / gridN, bn = swz % gridN;

    const int wave = tid >> 6, lane = tid & 63;
    const int wm   = wave >> 2, wn = wave & 3;
    const int lrow = lane & 15, lq = lane >> 4;

    const int key = (lrow & 7) << 3;
    const int e0  = (lq << 3) ^ key;
    const int e1  = e0 ^ 32;
    const int aRow = (wm * 64 + lrow) * 64;
    const int bRow = (wn * 32 + lrow) * 64;

    const int grow = lane >> 3;
    const int gswz = ((lane & 7) ^ (grow & 7)) << 3;
    const unsigned short* aS = A  + (size_t)(bm * 256 + grow) * lda + gswz;
    const unsigned short* bS = Bm + (size_t)(bn * 256 + grow) * ldb + gswz;

    f32x4 acc[8][4];
    #pragma unroll
    for (int i = 0; i < 8; ++i)
        #pragma unroll
        for (int n = 0; n < 4; ++n)
            acc[i][n] = (f32x4){0.f, 0.f, 0.f, 0.f};

    bfx8 areg[4][2], b0r[2][2], b1r[2][2];
    const int NT = K >> 6;   // even (K = 1024 or 2048)

    auto rdA = [&](const unsigned short* Ah) {
        #pragma unroll
        for (int i = 0; i < 4; ++i) {
            areg[i][0] = *(const bfx8*)(Ah + aRow + i * 1024 + e0);
            areg[i][1] = *(const bfx8*)(Ah + aRow + i * 1024 + e1);
        }
    };
    auto rdB = [&](const unsigned short* Bh, bfx8 (&br)[2][2]) {
        #pragma unroll
        for (int n = 0; n < 2; ++n) {
            br[n][0] = *(const bfx8*)(Bh + bRow + n * 1024 + e0);
            br[n][1] = *(const bfx8*)(Bh + bRow + n * 1024 + e1);
        }
    };
    auto mm = [&](int io, int no, bfx8 (&br)[2][2]) {
        __builtin_amdgcn_s_setprio(1);
        #pragma unroll
        for (int i = 0; i < 4; ++i)
            #pragma unroll
            for (int n = 0; n < 2; ++n)
                #pragma unroll
                for (int kk = 0; kk < 2; ++kk)
                    acc[io + i][no + n] = __builtin_amdgcn_mfma_f32_16x16x32_bf16(
                        areg[i][kk], br[n][kk], acc[io + i][no + n], 0, 0, 0);
        __builtin_amdgcn_s_setprio(0);
    };

#define WAITS() do { \
        if (deep) { asm volatile("s_waitcnt vmcnt(6)" ::: "memory"); } \
        else      { asm volatile("s_waitcnt vmcnt(0)" ::: "memory"); } \
        BAR(); \
        asm volatile("s_waitcnt lgkmcnt(0)" ::: "memory"); \
        SBAR(); \
    } while (0)

    // prologue
    stage_half(aS,                       lda, &lds[0][0][0],    wave);
    stage_half(bS,                       ldb, &lds[0][1][0],    wave);
    stage_half(bS + (size_t)128 * ldb,   ldb, &lds[0][1][8192], wave);
    stage_half(aS + (size_t)128 * lda,   lda, &lds[0][0][8192], wave);
    stage_half(aS + 64,                  lda, &lds[1][0][0],    wave);
    stage_half(bS + 64,                  ldb, &lds[1][1][0],    wave);
    asm volatile("s_waitcnt vmcnt(8)" ::: "memory");
    BAR();

    for (int T = 0; T < NT; T += 2) {
        const bool deep = (T + 2 < NT);
        const int k1 = (T + 1) << 6, k2 = (T + 2) << 6, k3 = (T + 3) << 6;

        rdA(&lds[0][0][0]); rdB(&lds[0][1][0], b0r);
        stage_half(bS + (size_t)128 * ldb + k1, ldb, &lds[1][1][8192], wave);
        WAITS(); mm(0, 0, b0r); BAR();

        rdB(&lds[0][1][8192], b1r);
        stage_half(aS + (size_t)128 * lda + k1, lda, &lds[1][0][8192], wave);
        WAITS(); mm(0, 2, b1r); BAR();

        rdA(&lds[0][0][8192]);
        if (deep) stage_half(aS + k2, lda, &lds[0][0][0], wave);
        WAITS(); mm(4, 2, b1r); BAR();

        if (deep) stage_half(bS + k2, ldb, &lds[0][1][0], wave);
        WAITS(); mm(4, 0, b0r); BAR();

        rdA(&lds[1][0][0]); rdB(&lds[1][1][0], b0r);
        if (deep) stage_half(bS + (size_t)128 * ldb + k2, ldb, &lds[0][1][8192], wave);
        WAITS(); mm(0, 0, b0r); BAR();

        rdB(&lds[1][1][8192], b1r);
        if (deep) stage_half(aS + (size_t)128 * lda + k2, lda, &lds[0][0][8192], wave);
        WAITS(); mm(0, 2, b1r); BAR();

        rdA(&lds[1][0][8192]);
        if (deep) stage_half(aS + k3, lda, &lds[1][0][0], wave);
        WAITS(); mm(4, 2, b1r); BAR();

        if (deep) stage_half(bS + k3, ldb, &lds[1][1][0], wave);
        WAITS(); mm(4, 0, b0r); BAR();
    }
#undef WAITS

    #pragma unroll
    for (int ai = 0; ai < 8; ++ai) {
        const int a = ai >> 2, i = ai & 3;
        const int row0 = bm * 256 + a * 128 + wm * 64 + i * 16 + lq * 4;
        #pragma unroll
        for (int c = 0; c < 4; ++c) {
            const int col = bn * 256 + (c >> 1) * 128 + wn * 32 + (c & 1) * 16 + lrow;
            float bv = 0.f;
            if (BIAS) bv = bias[col];
            #pragma unroll
            for (int r = 0; r < 4; ++r) {
                const float v = acc[ai][c][r] + bv;
                if constexpr (sizeof(TC) == 2)
                    C[(size_t)(row0 + r) * ldc + col] = (TC)f2bf(v);
                else
                    C[(size_t)(row0 + r) * ldc + col] = (TC)v;
            }
        }
    }
}

// ===========================================================================
// gemm128: 128x128 tile @ 2 blocks/CU (GEMM3)
// ===========================================================================
template<typename TC>
__global__ __launch_bounds__(256, 2) void gemm128(
    const unsigned short* __restrict__ A, int lda,
    const unsigned short* __restrict__ Bm, int ldb,
    TC* __restrict__ C, int ldc, int K, int gridN, int q8)
{
    __shared__ __align__(16) unsigned short lds[2][2][128 * 64]; // 64 KiB

    const int tid  = threadIdx.x;
    const int lin  = blockIdx.x;
    const int swz  = (lin & 7) * q8 + (lin >> 3);
    const int bm   = swz / gridN, bn = swz % gridN;

    const int wave = tid >> 6, lane = tid & 63;
    const int wm   = wave >> 1, wn = wave & 1;
    const int lrow = lane & 15, lq = lane >> 4;

    const int key = (lrow & 7) << 3;
    const int e0  = (lq << 3) ^ key;
    const int e1  = e0 ^ 32;
    const int aRow = (wm * 64 + lrow) * 64;
    const int bRow = (wn * 64 + lrow) * 64;

    const int grow = lane >> 3;
    const int gswz = ((lane & 7) ^ (grow & 7)) << 3;
    const unsigned short* aS = A  + (size_t)(bm * 128 + grow) * lda + gswz;
    const unsigned short* bS = Bm + (size_t)(bn * 128 + grow) * ldb + gswz;

    f32x4 acc[4][4];
    #pragma unroll
    for (int i = 0; i < 4; ++i)
        #pragma unroll
        for (int n = 0; n < 4; ++n)
            acc[i][n] = (f32x4){0.f, 0.f, 0.f, 0.f};

    bfx8 areg[4][2], breg[4][2];
    const int NT = K >> 6;

    stage_q(aS, lda, &lds[0][0][0], wave);
    stage_q(bS, ldb, &lds[0][1][0], wave);

    for (int t = 0; t < NT; ++t) {
        const int cur = t & 1, nxt = cur ^ 1;
        const unsigned short* Ac = lds[cur][0];
        const unsigned short* Bc = lds[cur][1];
        const bool hn = (t + 1 < NT);
        const int k1 = (t + 1) << 6;

        if (hn) {
            stage_q(aS + k1, lda, &lds[nxt][0][0], wave);
            stage_q(bS + k1, ldb, &lds[nxt][1][0], wave);
            asm volatile("s_waitcnt vmcnt(8)" ::: "memory");
        } else {
            asm volatile("s_waitcnt vmcnt(0)" ::: "memory");
        }
        BAR();

        #pragma unroll
        for (int i = 0; i < 4; ++i) {
            areg[i][0] = *(const bfx8*)(Ac + aRow + i * 1024 + e0);
            areg[i][1] = *(const bfx8*)(Ac + aRow + i * 1024 + e1);
        }
        #pragma unroll
        for (int n = 0; n < 4; ++n) {
            breg[n][0] = *(const bfx8*)(Bc + bRow + n * 1024 + e0);
            breg[n][1] = *(const bfx8*)(Bc + bRow + n * 1024 + e1);
        }
        #pragma unroll
        for (int i = 0; i < 4; ++i)
            #pragma unroll
            for (int n = 0; n < 4; ++n)
                #pragma unroll
                for (int kk = 0; kk < 2; ++kk)
                    acc[i][n] = __builtin_amdgcn_mfma_f32_16x16x32_bf16(areg[i][kk], breg[n][kk], acc[i][n], 0, 0, 0);
        BAR();
    }

    #pragma unroll
    for (int i = 0; i < 4; ++i) {
        const int row0 = bm * 128 + wm * 64 + i * 16 + lq * 4;
        #pragma unroll
        for (int n = 0; n < 4; ++n) {
            const int col = bn * 128 + wn * 64 + n * 16 + lrow;
            #pragma unroll
            for (int r = 0; r < 4; ++r) {
                const float v = acc[i][n][r];
                if constexpr (sizeof(TC) == 2)
                    C[(size_t)(row0 + r) * ldc + col] = (TC)f2bf(v);
                else
                    C[(size_t)(row0 + r) * ldc + col] = (TC)v;
            }
        }
    }
}

// ===========================================================================
// Fallback 128x128 GEMM for small workspace (r3 proven)
// ===========================================================================
template<typename T>
__device__ __forceinline__ void stage_op(const T* __restrict__ base, int ld, int k0,
                                         unsigned short* lds_, int tid)
{
    if constexpr (sizeof(T) == 2) {
        const int wave = tid >> 6, lane = tid & 63;
        const int grow = lane >> 3;
        const int gcol = (lane & 7) << 3;
        #pragma unroll
        for (int j = 0; j < 4; ++j) {
            const int r0 = wave * 32 + j * 8;
            gload_lds16((const unsigned short*)base + (size_t)(r0 + grow) * ld + k0 + gcol,
                        &lds_[r0 * 64]);
        }
    } else {
        const int srow = tid >> 4, scol = (tid & 15) << 2;
        #pragma unroll
        for (int p = 0; p < 8; ++p) {
            const int r = p * 16 + srow;
            const float4 v = *(const float4*)((const float*)base + (size_t)r * ld + k0 + scol);
            uint2 w;
            w.x = (unsigned)f2bf(v.x) | ((unsigned)f2bf(v.y) << 16);
            w.y = (unsigned)f2bf(v.z) | ((unsigned)f2bf(v.w) << 16);
            *(uint2*)&lds_[r * 64 + scol] = w;
        }
    }
}

template<typename TA, typename TB, typename TC, int BIAS>
__global__ __launch_bounds__(256) void gemm_bt(
    const TA* __restrict__ A, int lda,
    const TB* __restrict__ Bm, int ldb,
    TC* __restrict__ C, int ldc,
    const float* __restrict__ bias, int K)
{
    __shared__ __align__(16) unsigned short As[128 * 64];
    __shared__ __align__(16) unsigned short Bs[128 * 64];

    const int tid  = threadIdx.x;
    const int bm   = blockIdx.y, bn = blockIdx.x;
    const int wave = tid >> 6,  lane = tid & 63;
    const int wm   = wave >> 1, wn = wave & 1;
    const int lrow = lane & 15, lq = lane >> 4;

    f32x4 acc[4][4];
    #pragma unroll
    for (int i = 0; i < 4; ++i)
        #pragma unroll
        for (int j = 0; j < 4; ++j)
            acc[i][j] = (f32x4){0.f, 0.f, 0.f, 0.f};

    const TA* Abase = A  + (size_t)(bm * 128) * lda;
    const TB* Bbase = Bm + (size_t)(bn * 128) * ldb;

    for (int k0 = 0; k0 < K; k0 += 64) {
        stage_op<TA>(Abase, lda, k0, As, tid);
        stage_op<TB>(Bbase, ldb, k0, Bs, tid);
        __syncthreads();
        #pragma unroll
        for (int kk = 0; kk < 2; ++kk) {
            bfx8 af[4], bfr[4];
            const int kb = kk * 32 + lq * 8;
            #pragma unroll
            for (int m = 0; m < 4; ++m)
                af[m] = *(const bfx8*)&As[(wm * 64 + m * 16 + lrow) * 64 + kb];
            #pragma unroll
            for (int n = 0; n < 4; ++n)
                bfr[n] = *(const bfx8*)&Bs[(wn * 64 + n * 16 + lrow) * 64 + kb];
            #pragma unroll
            for (int m = 0; m < 4; ++m)
                #pragma unroll
                for (int n = 0; n < 4; ++n)
                    acc[m][n] = __builtin_amdgcn_mfma_f32_16x16x32_bf16(af[m], bfr[n], acc[m][n], 0, 0, 0);
        }
        __syncthreads();
    }

    #pragma unroll
    for (int m = 0; m < 4; ++m) {
        #pragma unroll
        for (int n = 0; n < 4; ++n) {
            const int row0 = bm * 128 + wm * 64 + m * 16 + lq * 4;
            const int col  = bn * 128 + wn * 64 + n * 16 + lrow;
            float bv = 0.f;
            if (BIAS) bv = bias[col];
            #pragma unroll
            for (int r = 0; r < 4; ++r) {
                const float v = acc[m][n][r] + bv;
                if constexpr (sizeof(TC) == 2)
                    C[(size_t)(row0 + r) * ldc + col] = (TC)f2bf(v);
                else
                    C[(size_t)(row0 + r) * ldc + col] = (TC)v;
            }
        }
    }
}

// ---------------------------------------------------------------------------
// fused fp32->bf16 convert of 4 segments (x, W_in, W_g, W_out), 8 elems/thread
// ---------------------------------------------------------------------------
__global__ __launch_bounds__(256) void cvt_all(
    const float* __restrict__ s0, unsigned short* __restrict__ d0, int n0,
    const float* __restrict__ s1, unsigned short* __restrict__ d1, int n1,
    const float* __restrict__ s2, unsigned short* __restrict__ d2, int n2,
    const float* __restrict__ s3, unsigned short* __restrict__ d3, int n3)
{
    int i = blockIdx.x * 256 + threadIdx.x;
    const float* src; unsigned short* dst;
    if (i < n0)                { src = s0; dst = d0; }
    else if ((i -= n0) < n1)   { src = s1; dst = d1; }
    else if ((i -= n1) < n2)   { src = s2; dst = d2; }
    else if ((i -= n2) < n3)   { src = s3; dst = d3; }
    else return;
    const float4 a = ((const float4*)src)[i * 2];
    const float4 b = ((const float4*)src)[i * 2 + 1];
    uint4 w;
    w.x = (unsigned)f2bf(a.x) | ((unsigned)f2bf(a.y) << 16);
    w.y = (unsigned)f2bf(a.z) | ((unsigned)f2bf(a.w) << 16);
    w.z = (unsigned)f2bf(b.x) | ((unsigned)f2bf(b.y) << 16);
    w.w = (unsigned)f2bf(b.z) | ((unsigned)f2bf(b.w) << 16);
    ((uint4*)dst)[i] = w;
}

// ---------------------------------------------------------------------------
// causal depthwise conv, K=4 (4h/thread — high-TLP proven geometry)
// ---------------------------------------------------------------------------
__global__ __launch_bounds__(256) void conv_k(
    const unsigned short* __restrict__ gi, const float* __restrict__ w,
    const float* __restrict__ cb, unsigned short* __restrict__ xc)
{
    const int idx = blockIdx.x * 256 + threadIdx.x;   // BTC*512
    const int h4 = idx & 511, bt = idx >> 9;
    const int h = h4 << 2;
    const int t = bt & (TTC - 1);

    float4 acc = *(const float4*)&cb[h];
    const float4 w0 = *(const float4*)&w[(h + 0) * 4];
    const float4 w1 = *(const float4*)&w[(h + 1) * 4];
    const float4 w2 = *(const float4*)&w[(h + 2) * 4];
    const float4 w3 = *(const float4*)&w[(h + 3) * 4];

    #pragma unroll
    for (int k = 0; k < 4; ++k) {
        const int tt = t - 3 + k;
        if (tt >= 0) {
            const ushort4 v = *(const ushort4*)&gi[(size_t)(bt - 3 + k) * 4096 + 2048 + h];
            const float a0 = (k == 0) ? w0.x : (k == 1) ? w0.y : (k == 2) ? w0.z : w0.w;
            const float a1 = (k == 0) ? w1.x : (k == 1) ? w1.y : (k == 2) ? w1.z : w1.w;
            const float a2 = (k == 0) ? w2.x : (k == 1) ? w2.y : (k == 2) ? w2.z : w2.w;
            const float a3 = (k == 0) ? w3.x : (k == 1) ? w3.y : (k == 2) ? w3.z : w3.w;
            acc.x += a0 * bf2f(v.x); acc.y += a1 * bf2f(v.y);
            acc.z += a2 * bf2f(v.z); acc.w += a3 * bf2f(v.w);
        }
    }
    ushort4 o;
    o.x = f2bf(acc.x); o.y = f2bf(acc.y); o.z = f2bf(acc.z); o.w = f2bf(acc.w);
    *(ushort4*)&xc[(size_t)bt * 2048 + h] = o;
}

// ---------------------------------------------------------------------------
// scan passes (scalar 1h/thread, NCHUNK=64 — high-TLP proven geometry)
// ---------------------------------------------------------------------------
__global__ __launch_bounds__(256) void scan1(
    const unsigned short* __restrict__ g, const unsigned short* __restrict__ xc,
    const float* __restrict__ fb, float2* __restrict__ sums)
{
    const int idx = blockIdx.x * 256 + threadIdx.x;   // 2^19
    const int h = idx & (HIDC - 1);
    const int c = (idx >> 11) & (NCHUNK - 1);
    const int b = idx >> 17;

    const float c1 = -8.0f * log1pf(expf(fb[h]));
    float pA = 1.f, hl = 0.f;
    const int row0 = b * TTC + c * CLEN;

    for (int tl = 0; tl < CLEN; ++tl) {
        const size_t row = (size_t)(row0 + tl);
        const float f   = bf2f(g[row * 4096 + h]);
        const float gin = bf2f(g[row * 4096 + 2048 + h]);
        const float xv  = bf2f(xc[row * 2048 + h]);
        const float sf = 1.f / (1.f + expf(-f));
        const float a  = expf(c1 * sf);
        const float be = sqrtf(1.f - a * a + 1e-6f);
        const float si = 1.f / (1.f + expf(-gin));
        hl = a * hl + be * si * xv;
        pA *= a;
    }
    sums[(size_t)(c * BBC + b) * HIDC + h] = make_float2(pA, hl);
}

// scan2: batched summary loads (8 in flight) — latency-chain fix, geometry unchanged
__global__ __launch_bounds__(256) void scan2(
    const float2* __restrict__ sums, float* __restrict__ carry)
{
    const int idx = blockIdx.x * 256 + threadIdx.x;   // BBC*HIDC = 8192
    const int h = idx & (HIDC - 1), b = idx >> 11;
    float cy = 0.f;
    for (int c0 = 0; c0 < NCHUNK; c0 += 8) {
        float2 s[8];
        #pragma unroll
        for (int j = 0; j < 8; ++j)
            s[j] = sums[(size_t)((c0 + j) * BBC + b) * HIDC + h];
        #pragma unroll
        for (int j = 0; j < 8; ++j) {
            carry[(size_t)((c0 + j) * BBC + b) * HIDC + h] = cy;
            cy = s[j].y + s[j].x * cy;
        }
    }
}

__global__ __launch_bounds__(256) void scan3(
    unsigned short* __restrict__ gi, const unsigned short* __restrict__ g,
    const unsigned short* __restrict__ xc, const float* __restrict__ fb,
    const float* __restrict__ carry)
{
    const int idx = blockIdx.x * 256 + threadIdx.x;   // 2^19
    const int h = idx & (HIDC - 1);
    const int c = (idx >> 11) & (NCHUNK - 1);
    const int b = idx >> 17;

    const float c1 = -8.0f * log1pf(expf(fb[h]));
    float hh = carry[(size_t)(c * BBC + b) * HIDC + h];
    const int row0 = b * TTC + c * CLEN;

    for (int tl = 0; tl < CLEN; ++tl) {
        const size_t row = (size_t)(row0 + tl);
        const float f    = bf2f(g[row * 4096 + h]);
        const float gin  = bf2f(g[row * 4096 + 2048 + h]);
        const float xv   = bf2f(xc[row * 2048 + h]);
        const float gate = bf2f(gi[row * 4096 + h]);
        const float sf = 1.f / (1.f + expf(-f));
        const float a  = expf(c1 * sf);
        const float be = sqrtf(1.f - a * a + 1e-6f);
        const float si = 1.f / (1.f + expf(-gin));
        hh = a * hh + be * si * xv;
        gi[row * 4096 + h] = f2bf(gelu_exact(gate) * hh);
    }
}

// ---------------------------------------------------------------------------
extern "C" void kernel_launch(void* const* d_in, const int* in_sizes, int n_in,
                              void* d_out, int out_size, void* d_ws, size_t ws_size,
                              hipStream_t stream)
{
    const float* x     = (const float*)d_in[0];
    const float* W_in  = (const float*)d_in[1];
    const float* cw    = (const float*)d_in[2];
    const float* cb    = (const float*)d_in[3];
    const float* W_g   = (const float*)d_in[4];
    const float* b_g   = (const float*)d_in[5];
    const float* fb    = (const float*)d_in[6];
    const float* W_out = (const float*)d_in[7];
    float* out = (float*)d_out;

    const size_t n_gi  = (size_t)BTC * 4096;            // bf16
    const size_t n_g   = (size_t)BTC * 4096;            // bf16
    const size_t n_xc  = (size_t)BTC * 2048;            // bf16
    const size_t n_sum = (size_t)NCHUNK * BBC * HIDC;   // float2 / float
    const size_t nX    = (size_t)BTC * DIMC;
    const size_t nWin  = (size_t)4096 * 1024;
    const size_t nWg   = (size_t)4096 * 2048;
    const size_t nWout = (size_t)1024 * 2048;

    const size_t need_base = (n_gi + n_g + n_xc) * 2 + n_sum * 12;     // 166 MiB
    const size_t need_full = need_base + (nWg + nWout) * 2;            // 186 MiB
    if (ws_size < need_base) return;
    const bool use8 = (ws_size >= need_full);

    unsigned short* gi = (unsigned short*)d_ws;
    unsigned short* g  = gi + n_gi;
    unsigned short* xc = g + n_g;
    float2* sums  = (float2*)(xc + n_xc);
    float*  carry = (float*)(sums + n_sum);
    unsigned short* wg_bf   = (unsigned short*)(carry + n_sum);
    unsigned short* wout_bf = wg_bf + nWg;
    unsigned short* x_bf   = g;            // aliases g (dead until GEMM2)
    unsigned short* win_bf = g + nX;

    if (use8) {
        const int n0 = (int)(nX / 8), n1 = (int)(nWin / 8),
                  n2 = (int)(nWg / 8), n3 = (int)(nWout / 8);
        cvt_all<<<(n0 + n1 + n2 + n3 + 255) / 256, 256, 0, stream>>>(
            x, x_bf, n0, W_in, win_bf, n1, W_g, wg_bf, n2, W_out, wout_bf, n3);

        // GEMM1: gi = x @ W_in^T        M=8192 N=4096 K=1024   nwg=512
        gemm8x<unsigned short, 0><<<512, 512, 0, stream>>>(
            x_bf, DIMC, win_bf, DIMC, gi, 4096, nullptr, DIMC, 16, 64);

        conv_k<<<(BTC * 512) / 256, 256, 0, stream>>>(gi, cw, cb, xc);

        // GEMM2: g = xc @ W_g^T + b_g   M=8192 N=4096 K=2048   nwg=512
        gemm8x<unsigned short, 1><<<512, 512, 0, stream>>>(
            xc, HIDC, wg_bf, HIDC, g, 4096, b_g, HIDC, 16, 64);

        scan1<<<(BBC * NCHUNK * HIDC) / 256, 256, 0, stream>>>(g, xc, fb, sums);
        scan2<<<(BBC * HIDC) / 256, 256, 0, stream>>>(sums, carry);
        scan3<<<(BBC * NCHUNK * HIDC) / 256, 256, 0, stream>>>(gi, g, xc, fb, carry);

        // GEMM3: out = u @ W_out^T      M=8192 N=1024 K=2048   gemm128 512 blocks
        gemm128<float><<<512, 256, 0, stream>>>(
            gi, 4096, wout_bf, HIDC, out, DIMC, HIDC, 8, 64);
    } else {
        gemm_bt<float, float, unsigned short, 0>
            <<<dim3(4096 / 128, BTC / 128), 256, 0, stream>>>(
            x, DIMC, W_in, DIMC, gi, 4096, nullptr, DIMC);
        conv_k<<<(BTC * 512) / 256, 256, 0, stream>>>(gi, cw, cb, xc);
        gemm_bt<unsigned short, float, unsigned short, 1>
            <<<dim3(4096 / 128, BTC / 128), 256, 0, stream>>>(
            xc, HIDC, W_g, HIDC, g, 4096, b_g, HIDC);
        scan1<<<(BBC * NCHUNK * HIDC) / 256, 256, 0, stream>>>(g, xc, fb, sums);
        scan2<<<(BBC * HIDC) / 256, 256, 0, stream>>>(sums, carry);
        scan3<<<(BBC * NCHUNK * HIDC) / 256, 256, 0, stream>>>(gi, g, xc, fb, carry);
        gemm_bt<unsigned short, float, float, 0>
            <<<dim3(DIMC / 128, BTC / 128), 256, 0, stream>>>(
            gi, 4096, W_out, HIDC, out, DIMC, nullptr, HIDC);
    }
}

// Round 13
// 397.211 us; speedup vs baseline: 1.1486x; 1.0102x over previous
//
#include <hip/hip_runtime.h>
#include <hip/hip_bf16.h>
#include <math.h>

// RG-LRU block: GEMM1 -> depthwise causal conv -> GEMM2 -> chunked linear scan -> GEMM3
// r12 base (401.3us). One change: gemm8x vmcnt moved to K-tile boundaries only
// (template T4 rule: waits at ph0/ph4, not every phase). FIFO ledger verified.

#define HIDC 2048
#define DIMC 1024
#define BBC 4
#define TTC 2048
#define BTC (BBC*TTC)      // 8192 rows
#define NCHUNK 64
#define CLEN 32            // TTC / NCHUNK

typedef __attribute__((ext_vector_type(8))) short bfx8;
typedef __attribute__((ext_vector_type(4))) float f32x4;

__device__ __forceinline__ unsigned short f2bf(float f) {
    return __builtin_bit_cast(unsigned short, __float2bfloat16(f));
}
__device__ __forceinline__ float bf2f(unsigned short u) {
    union { unsigned int i; float f; } v; v.i = ((unsigned)u) << 16; return v.f;
}
__device__ __forceinline__ float gelu_exact(float x) {
    return 0.5f * x * (1.0f + erff(x * 0.70710678118654752f));
}

typedef const unsigned int __attribute__((address_space(1)))* gas_ptr;
typedef unsigned int __attribute__((address_space(3)))* las_ptr;
__device__ __forceinline__ void gload_lds16(const void* g, void* l) {
    __builtin_amdgcn_global_load_lds((gas_ptr)g, (las_ptr)l, 16, 0, 0);
}

// Stage one 128-row x 64-col bf16 half-tile with 8 waves (2 gloads/wave).
__device__ __forceinline__ void stage_half(
    const unsigned short* __restrict__ gsrc,
    int ld, unsigned short* ldsdst, int wave)
{
    #pragma unroll
    for (int j = 0; j < 2; ++j) {
        const int r0 = (wave * 2 + j) * 8;
        gload_lds16(gsrc + (size_t)r0 * ld, ldsdst + r0 * 64);
    }
}
// Stage one 128-row x 64-col bf16 tile with 4 waves (4 gloads/wave).
__device__ __forceinline__ void stage_q(
    const unsigned short* __restrict__ gsrc,
    int ld, unsigned short* ldsdst, int wave)
{
    #pragma unroll
    for (int j = 0; j < 4; ++j) {
        const int r0 = (wave * 4 + j) * 8;
        gload_lds16(gsrc + (size_t)r0 * ld, ldsdst + r0 * 64);
    }
}

#define SBAR()  __builtin_amdgcn_sched_barrier(0)
#define BAR()   do { SBAR(); __builtin_amdgcn_s_barrier(); SBAR(); } while (0)

// ===========================================================================
// gemm8x: 256x256 tile, BK=64, 8 waves (2Mx4N), 8 phases per 2 K-tiles.
// vmcnt ONLY at ph0/ph4 (K-tile boundaries), per m201 template T4 rule.
// Ledger: ph0 vmcnt(6) leaves newest 3 halves {A0,B0,B1(T+1)} outstanding ->
// tile T fully retired; ph4 vmcnt(6) leaves {A0,B0,B1(T+2)} -> tile T+1
// retired. Tail pair: ph0 vmcnt(6), ph4 vmcnt(0). Barriers/stages unchanged.
// ===========================================================================
template<typename TC, int BIAS>
__global__ __launch_bounds__(512, 2) void gemm8x(
    const unsigned short* __restrict__ A, int lda,
    const unsigned short* __restrict__ Bm, int ldb,
    TC* __restrict__ C, int ldc,
    const float* __restrict__ bias, int K, int gridN, int q8)
{
    __shared__ __align__(16) unsigned short lds[2][2][256 * 64]; // [buf][A/B]

    const int tid  = threadIdx.x;
    const int lin  = blockIdx.x;
    const int swz  = (lin & 7) * q8 + (lin >> 3);      // XCD swizzle (nwg%8==0)
    const int bm   = swz / gridN, bn = swz % gridN;

    const int wave = tid >> 6, lane = tid & 63;
    const int wm   = wave >> 2, wn = wave & 3;
    const int lrow = lane & 15, lq = lane >> 4;

    const int key = (lrow & 7) << 3;
    const int e0  = (lq << 3) ^ key;
    const int e1  = e0 ^ 32;
    const int aRow = (wm * 64 + lrow) * 64;
    const int bRow = (wn * 32 + lrow) * 64;

    const int grow = lane >> 3;
    const int gswz = ((lane & 7) ^ (grow & 7)) << 3;
    const unsigned short* aS = A  + (size_t)(bm * 256 + grow) * lda + gswz;
    const unsigned short* bS = Bm + (size_t)(bn * 256 + grow) * ldb + gswz;

    f32x4 acc[8][4];
    #pragma unroll
    for (int i = 0; i < 8; ++i)
        #pragma unroll
        for (int n = 0; n < 4; ++n)
            acc[i][n] = (f32x4){0.f, 0.f, 0.f, 0.f};

    bfx8 areg[4][2], b0r[2][2], b1r[2][2];
    const int NT = K >> 6;   // even (K = 1024 or 2048)

    auto rdA = [&](const unsigned short* Ah) {
        #pragma unroll
        for (int i = 0; i < 4; ++i) {
            areg[i][0] = *(const bfx8*)(Ah + aRow + i * 1024 + e0);
            areg[i][1] = *(const bfx8*)(Ah + aRow + i * 1024 + e1);
        }
    };
    auto rdB = [&](const unsigned short* Bh, bfx8 (&br)[2][2]) {
        #pragma unroll
        for (int n = 0; n < 2; ++n) {
            br[n][0] = *(const bfx8*)(Bh + bRow + n * 1024 + e0);
            br[n][1] = *(const bfx8*)(Bh + bRow + n * 1024 + e1);
        }
    };
    auto mm = [&](int io, int no, bfx8 (&br)[2][2]) {
        __builtin_amdgcn_s_setprio(1);
        #pragma unroll
        for (int i = 0; i < 4; ++i)
            #pragma unroll
            for (int n = 0; n < 2; ++n)
                #pragma unroll
                for (int kk = 0; kk < 2; ++kk)
                    acc[io + i][no + n] = __builtin_amdgcn_mfma_f32_16x16x32_bf16(
                        areg[i][kk], br[n][kk], acc[io + i][no + n], 0, 0, 0);
        __builtin_amdgcn_s_setprio(0);
    };

// phase separator WITHOUT vmcnt (data readiness handled at ph0/ph4 only)
#define PSEP() do { \
        BAR(); \
        asm volatile("s_waitcnt lgkmcnt(0)" ::: "memory"); \
        SBAR(); \
    } while (0)

    // prologue
    stage_half(aS,                       lda, &lds[0][0][0],    wave);
    stage_half(bS,                       ldb, &lds[0][1][0],    wave);
    stage_half(bS + (size_t)128 * ldb,   ldb, &lds[0][1][8192], wave);
    stage_half(aS + (size_t)128 * lda,   lda, &lds[0][0][8192], wave);
    stage_half(aS + 64,                  lda, &lds[1][0][0],    wave);
    stage_half(bS + 64,                  ldb, &lds[1][1][0],    wave);
    asm volatile("s_waitcnt vmcnt(8)" ::: "memory");
    BAR();

    for (int T = 0; T < NT; T += 2) {
        const bool deep = (T + 2 < NT);
        const int k1 = (T + 1) << 6, k2 = (T + 2) << 6, k3 = (T + 3) << 6;

        // ph0: read A0,B0(T) | stage B1(T+1) | vmcnt(6): tile T fully retired
        rdA(&lds[0][0][0]); rdB(&lds[0][1][0], b0r);
        stage_half(bS + (size_t)128 * ldb + k1, ldb, &lds[1][1][8192], wave);
        asm volatile("s_waitcnt vmcnt(6)" ::: "memory");
        PSEP(); mm(0, 0, b0r); BAR();

        // ph1: read B1(T) | stage A1(T+1)
        rdB(&lds[0][1][8192], b1r);
        stage_half(aS + (size_t)128 * lda + k1, lda, &lds[1][0][8192], wave);
        PSEP(); mm(0, 2, b1r); BAR();

        // ph2: read A1(T) | stage A0(T+2)
        rdA(&lds[0][0][8192]);
        if (deep) stage_half(aS + k2, lda, &lds[0][0][0], wave);
        PSEP(); mm(4, 2, b1r); BAR();

        // ph3: no reads | stage B0(T+2)
        if (deep) stage_half(bS + k2, ldb, &lds[0][1][0], wave);
        PSEP(); mm(4, 0, b0r); BAR();

        // ph4: read A0,B0(T+1) | stage B1(T+2) | vmcnt: tile T+1 retired
        rdA(&lds[1][0][0]); rdB(&lds[1][1][0], b0r);
        if (deep) {
            stage_half(bS + (size_t)128 * ldb + k2, ldb, &lds[0][1][8192], wave);
            asm volatile("s_waitcnt vmcnt(6)" ::: "memory");
        } else {
            asm volatile("s_waitcnt vmcnt(0)" ::: "memory");
        }
        PSEP(); mm(0, 0, b0r); BAR();

        // ph5: read B1(T+1) | stage A1(T+2)
        rdB(&lds[1][1][8192], b1r);
        if (deep) stage_half(aS + (size_t)128 * lda + k2, lda, &lds[0][0][8192], wave);
        PSEP(); mm(0, 2, b1r); BAR();

        // ph6: read A1(T+1) | stage A0(T+3)
        rdA(&lds[1][0][8192]);
        if (deep) stage_half(aS + k3, lda, &lds[1][0][0], wave);
        PSEP(); mm(4, 2, b1r); BAR();

        // ph7: no reads | stage B0(T+3)
        if (deep) stage_half(bS + k3, ldb, &lds[1][1][0], wave);
        PSEP(); mm(4, 0, b0r); BAR();
    }
#undef PSEP

    // epilogue: C/D layout col=lane&15, row=(lane>>4)*4+reg
    #pragma unroll
    for (int ai = 0; ai < 8; ++ai) {
        const int a = ai >> 2, i = ai & 3;
        const int row0 = bm * 256 + a * 128 + wm * 64 + i * 16 + lq * 4;
        #pragma unroll
        for (int c = 0; c < 4; ++c) {
            const int col = bn * 256 + (c >> 1) * 128 + wn * 32 + (c & 1) * 16 + lrow;
            float bv = 0.f;
            if (BIAS) bv = bias[col];
            #pragma unroll
            for (int r = 0; r < 4; ++r) {
                const float v = acc[ai][c][r] + bv;
                if constexpr (sizeof(TC) == 2)
                    C[(size_t)(row0 + r) * ldc + col] = (TC)f2bf(v);
                else
                    C[(size_t)(row0 + r) * ldc + col] = (TC)v;
            }
        }
    }
}

// ===========================================================================
// gemm128: 128x128 tile @ 2 blocks/CU (GEMM3)
// ===========================================================================
template<typename TC>
__global__ __launch_bounds__(256, 2) void gemm128(
    const unsigned short* __restrict__ A, int lda,
    const unsigned short* __restrict__ Bm, int ldb,
    TC* __restrict__ C, int ldc, int K, int gridN, int q8)
{
    __shared__ __align__(16) unsigned short lds[2][2][128 * 64]; // 64 KiB

    const int tid  = threadIdx.x;
    const int lin  = blockIdx.x;
    const int swz  = (lin & 7) * q8 + (lin >> 3);
    const int bm   = swz / gridN, bn = swz % gridN;

    const int wave = tid >> 6, lane = tid & 63;
    const int wm   = wave >> 1, wn = wave & 1;
    const int lrow = lane & 15, lq = lane >> 4;

    const int key = (lrow & 7) << 3;
    const int e0  = (lq << 3) ^ key;
    const int e1  = e0 ^ 32;
    const int aRow = (wm * 64 + lrow) * 64;
    const int bRow = (wn * 64 + lrow) * 64;

    const int grow = lane >> 3;
    const int gswz = ((lane & 7) ^ (grow & 7)) << 3;
    const unsigned short* aS = A  + (size_t)(bm * 128 + grow) * lda + gswz;
    const unsigned short* bS = Bm + (size_t)(bn * 128 + grow) * ldb + gswz;

    f32x4 acc[4][4];
    #pragma unroll
    for (int i = 0; i < 4; ++i)
        #pragma unroll
        for (int n = 0; n < 4; ++n)
            acc[i][n] = (f32x4){0.f, 0.f, 0.f, 0.f};

    bfx8 areg[4][2], breg[4][2];
    const int NT = K >> 6;

    stage_q(aS, lda, &lds[0][0][0], wave);
    stage_q(bS, ldb, &lds[0][1][0], wave);

    for (int t = 0; t < NT; ++t) {
        const int cur = t & 1, nxt = cur ^ 1;
        const unsigned short* Ac = lds[cur][0];
        const unsigned short* Bc = lds[cur][1];
        const bool hn = (t + 1 < NT);
        const int k1 = (t + 1) << 6;

        if (hn) {
            stage_q(aS + k1, lda, &lds[nxt][0][0], wave);
            stage_q(bS + k1, ldb, &lds[nxt][1][0], wave);
            asm volatile("s_waitcnt vmcnt(8)" ::: "memory");
        } else {
            asm volatile("s_waitcnt vmcnt(0)" ::: "memory");
        }
        BAR();

        #pragma unroll
        for (int i = 0; i < 4; ++i) {
            areg[i][0] = *(const bfx8*)(Ac + aRow + i * 1024 + e0);
            areg[i][1] = *(const bfx8*)(Ac + aRow + i * 1024 + e1);
        }
        #pragma unroll
        for (int n = 0; n < 4; ++n) {
            breg[n][0] = *(const bfx8*)(Bc + bRow + n * 1024 + e0);
            breg[n][1] = *(const bfx8*)(Bc + bRow + n * 1024 + e1);
        }
        #pragma unroll
        for (int i = 0; i < 4; ++i)
            #pragma unroll
            for (int n = 0; n < 4; ++n)
                #pragma unroll
                for (int kk = 0; kk < 2; ++kk)
                    acc[i][n] = __builtin_amdgcn_mfma_f32_16x16x32_bf16(areg[i][kk], breg[n][kk], acc[i][n], 0, 0, 0);
        BAR();
    }

    #pragma unroll
    for (int i = 0; i < 4; ++i) {
        const int row0 = bm * 128 + wm * 64 + i * 16 + lq * 4;
        #pragma unroll
        for (int n = 0; n < 4; ++n) {
            const int col = bn * 128 + wn * 64 + n * 16 + lrow;
            #pragma unroll
            for (int r = 0; r < 4; ++r) {
                const float v = acc[i][n][r];
                if constexpr (sizeof(TC) == 2)
                    C[(size_t)(row0 + r) * ldc + col] = (TC)f2bf(v);
                else
                    C[(size_t)(row0 + r) * ldc + col] = (TC)v;
            }
        }
    }
}

// ===========================================================================
// Fallback 128x128 GEMM for small workspace (r3 proven)
// ===========================================================================
template<typename T>
__device__ __forceinline__ void stage_op(const T* __restrict__ base, int ld, int k0,
                                         unsigned short* lds_, int tid)
{
    if constexpr (sizeof(T) == 2) {
        const int wave = tid >> 6, lane = tid & 63;
        const int grow = lane >> 3;
        const int gcol = (lane & 7) << 3;
        #pragma unroll
        for (int j = 0; j < 4; ++j) {
            const int r0 = wave * 32 + j * 8;
            gload_lds16((const unsigned short*)base + (size_t)(r0 + grow) * ld + k0 + gcol,
                        &lds_[r0 * 64]);
        }
    } else {
        const int srow = tid >> 4, scol = (tid & 15) << 2;
        #pragma unroll
        for (int p = 0; p < 8; ++p) {
            const int r = p * 16 + srow;
            const float4 v = *(const float4*)((const float*)base + (size_t)r * ld + k0 + scol);
            uint2 w;
            w.x = (unsigned)f2bf(v.x) | ((unsigned)f2bf(v.y) << 16);
            w.y = (unsigned)f2bf(v.z) | ((unsigned)f2bf(v.w) << 16);
            *(uint2*)&lds_[r * 64 + scol] = w;
        }
    }
}

template<typename TA, typename TB, typename TC, int BIAS>
__global__ __launch_bounds__(256) void gemm_bt(
    const TA* __restrict__ A, int lda,
    const TB* __restrict__ Bm, int ldb,
    TC* __restrict__ C, int ldc,
    const float* __restrict__ bias, int K)
{
    __shared__ __align__(16) unsigned short As[128 * 64];
    __shared__ __align__(16) unsigned short Bs[128 * 64];

    const int tid  = threadIdx.x;
    const int bm   = blockIdx.y, bn = blockIdx.x;
    const int wave = tid >> 6,  lane = tid & 63;
    const int wm   = wave >> 1, wn = wave & 1;
    const int lrow = lane & 15, lq = lane >> 4;

    f32x4 acc[4][4];
    #pragma unroll
    for (int i = 0; i < 4; ++i)
        #pragma unroll
        for (int j = 0; j < 4; ++j)
            acc[i][j] = (f32x4){0.f, 0.f, 0.f, 0.f};

    const TA* Abase = A  + (size_t)(bm * 128) * lda;
    const TB* Bbase = Bm + (size_t)(bn * 128) * ldb;

    for (int k0 = 0; k0 < K; k0 += 64) {
        stage_op<TA>(Abase, lda, k0, As, tid);
        stage_op<TB>(Bbase, ldb, k0, Bs, tid);
        __syncthreads();
        #pragma unroll
        for (int kk = 0; kk < 2; ++kk) {
            bfx8 af[4], bfr[4];
            const int kb = kk * 32 + lq * 8;
            #pragma unroll
            for (int m = 0; m < 4; ++m)
                af[m] = *(const bfx8*)&As[(wm * 64 + m * 16 + lrow) * 64 + kb];
            #pragma unroll
            for (int n = 0; n < 4; ++n)
                bfr[n] = *(const bfx8*)&Bs[(wn * 64 + n * 16 + lrow) * 64 + kb];
            #pragma unroll
            for (int m = 0; m < 4; ++m)
                #pragma unroll
                for (int n = 0; n < 4; ++n)
                    acc[m][n] = __builtin_amdgcn_mfma_f32_16x16x32_bf16(af[m], bfr[n], acc[m][n], 0, 0, 0);
        }
        __syncthreads();
    }

    #pragma unroll
    for (int m = 0; m < 4; ++m) {
        #pragma unroll
        for (int n = 0; n < 4; ++n) {
            const int row0 = bm * 128 + wm * 64 + m * 16 + lq * 4;
            const int col  = bn * 128 + wn * 64 + n * 16 + lrow;
            float bv = 0.f;
            if (BIAS) bv = bias[col];
            #pragma unroll
            for (int r = 0; r < 4; ++r) {
                const float v = acc[m][n][r] + bv;
                if constexpr (sizeof(TC) == 2)
                    C[(size_t)(row0 + r) * ldc + col] = (TC)f2bf(v);
                else
                    C[(size_t)(row0 + r) * ldc + col] = (TC)v;
            }
        }
    }
}

// ---------------------------------------------------------------------------
// fused fp32->bf16 convert of 4 segments (x, W_in, W_g, W_out), 8 elems/thread
// ---------------------------------------------------------------------------
__global__ __launch_bounds__(256) void cvt_all(
    const float* __restrict__ s0, unsigned short* __restrict__ d0, int n0,
    const float* __restrict__ s1, unsigned short* __restrict__ d1, int n1,
    const float* __restrict__ s2, unsigned short* __restrict__ d2, int n2,
    const float* __restrict__ s3, unsigned short* __restrict__ d3, int n3)
{
    int i = blockIdx.x * 256 + threadIdx.x;
    const float* src; unsigned short* dst;
    if (i < n0)                { src = s0; dst = d0; }
    else if ((i -= n0) < n1)   { src = s1; dst = d1; }
    else if ((i -= n1) < n2)   { src = s2; dst = d2; }
    else if ((i -= n2) < n3)   { src = s3; dst = d3; }
    else return;
    const float4 a = ((const float4*)src)[i * 2];
    const float4 b = ((const float4*)src)[i * 2 + 1];
    uint4 w;
    w.x = (unsigned)f2bf(a.x) | ((unsigned)f2bf(a.y) << 16);
    w.y = (unsigned)f2bf(a.z) | ((unsigned)f2bf(a.w) << 16);
    w.z = (unsigned)f2bf(b.x) | ((unsigned)f2bf(b.y) << 16);
    w.w = (unsigned)f2bf(b.z) | ((unsigned)f2bf(b.w) << 16);
    ((uint4*)dst)[i] = w;
}

// ---------------------------------------------------------------------------
// causal depthwise conv, K=4 (4h/thread — high-TLP proven geometry)
// ---------------------------------------------------------------------------
__global__ __launch_bounds__(256) void conv_k(
    const unsigned short* __restrict__ gi, const float* __restrict__ w,
    const float* __restrict__ cb, unsigned short* __restrict__ xc)
{
    const int idx = blockIdx.x * 256 + threadIdx.x;   // BTC*512
    const int h4 = idx & 511, bt = idx >> 9;
    const int h = h4 << 2;
    const int t = bt & (TTC - 1);

    float4 acc = *(const float4*)&cb[h];
    const float4 w0 = *(const float4*)&w[(h + 0) * 4];
    const float4 w1 = *(const float4*)&w[(h + 1) * 4];
    const float4 w2 = *(const float4*)&w[(h + 2) * 4];
    const float4 w3 = *(const float4*)&w[(h + 3) * 4];

    #pragma unroll
    for (int k = 0; k < 4; ++k) {
        const int tt = t - 3 + k;
        if (tt >= 0) {
            const ushort4 v = *(const ushort4*)&gi[(size_t)(bt - 3 + k) * 4096 + 2048 + h];
            const float a0 = (k == 0) ? w0.x : (k == 1) ? w0.y : (k == 2) ? w0.z : w0.w;
            const float a1 = (k == 0) ? w1.x : (k == 1) ? w1.y : (k == 2) ? w1.z : w1.w;
            const float a2 = (k == 0) ? w2.x : (k == 1) ? w2.y : (k == 2) ? w2.z : w2.w;
            const float a3 = (k == 0) ? w3.x : (k == 1) ? w3.y : (k == 2) ? w3.z : w3.w;
            acc.x += a0 * bf2f(v.x); acc.y += a1 * bf2f(v.y);
            acc.z += a2 * bf2f(v.z); acc.w += a3 * bf2f(v.w);
        }
    }
    ushort4 o;
    o.x = f2bf(acc.x); o.y = f2bf(acc.y); o.z = f2bf(acc.z); o.w = f2bf(acc.w);
    *(ushort4*)&xc[(size_t)bt * 2048 + h] = o;
}

// ---------------------------------------------------------------------------
// scan passes (scalar 1h/thread, NCHUNK=64 — high-TLP proven geometry)
// ---------------------------------------------------------------------------
__global__ __launch_bounds__(256) void scan1(
    const unsigned short* __restrict__ g, const unsigned short* __restrict__ xc,
    const float* __restrict__ fb, float2* __restrict__ sums)
{
    const int idx = blockIdx.x * 256 + threadIdx.x;   // 2^19
    const int h = idx & (HIDC - 1);
    const int c = (idx >> 11) & (NCHUNK - 1);
    const int b = idx >> 17;

    const float c1 = -8.0f * log1pf(expf(fb[h]));
    float pA = 1.f, hl = 0.f;
    const int row0 = b * TTC + c * CLEN;

    for (int tl = 0; tl < CLEN; ++tl) {
        const size_t row = (size_t)(row0 + tl);
        const float f   = bf2f(g[row * 4096 + h]);
        const float gin = bf2f(g[row * 4096 + 2048 + h]);
        const float xv  = bf2f(xc[row * 2048 + h]);
        const float sf = 1.f / (1.f + expf(-f));
        const float a  = expf(c1 * sf);
        const float be = sqrtf(1.f - a * a + 1e-6f);
        const float si = 1.f / (1.f + expf(-gin));
        hl = a * hl + be * si * xv;
        pA *= a;
    }
    sums[(size_t)(c * BBC + b) * HIDC + h] = make_float2(pA, hl);
}

// scan2: batched summary loads (8 in flight) — latency-chain fix
__global__ __launch_bounds__(256) void scan2(
    const float2* __restrict__ sums, float* __restrict__ carry)
{
    const int idx = blockIdx.x * 256 + threadIdx.x;   // BBC*HIDC = 8192
    const int h = idx & (HIDC - 1), b = idx >> 11;
    float cy = 0.f;
    for (int c0 = 0; c0 < NCHUNK; c0 += 8) {
        float2 s[8];
        #pragma unroll
        for (int j = 0; j < 8; ++j)
            s[j] = sums[(size_t)((c0 + j) * BBC + b) * HIDC + h];
        #pragma unroll
        for (int j = 0; j < 8; ++j) {
            carry[(size_t)((c0 + j) * BBC + b) * HIDC + h] = cy;
            cy = s[j].y + s[j].x * cy;
        }
    }
}

__global__ __launch_bounds__(256) void scan3(
    unsigned short* __restrict__ gi, const unsigned short* __restrict__ g,
    const unsigned short* __restrict__ xc, const float* __restrict__ fb,
    const float* __restrict__ carry)
{
    const int idx = blockIdx.x * 256 + threadIdx.x;   // 2^19
    const int h = idx & (HIDC - 1);
    const int c = (idx >> 11) & (NCHUNK - 1);
    const int b = idx >> 17;

    const float c1 = -8.0f * log1pf(expf(fb[h]));
    float hh = carry[(size_t)(c * BBC + b) * HIDC + h];
    const int row0 = b * TTC + c * CLEN;

    for (int tl = 0; tl < CLEN; ++tl) {
        const size_t row = (size_t)(row0 + tl);
        const float f    = bf2f(g[row * 4096 + h]);
        const float gin  = bf2f(g[row * 4096 + 2048 + h]);
        const float xv   = bf2f(xc[row * 2048 + h]);
        const float gate = bf2f(gi[row * 4096 + h]);
        const float sf = 1.f / (1.f + expf(-f));
        const float a  = expf(c1 * sf);
        const float be = sqrtf(1.f - a * a + 1e-6f);
        const float si = 1.f / (1.f + expf(-gin));
        hh = a * hh + be * si * xv;
        gi[row * 4096 + h] = f2bf(gelu_exact(gate) * hh);
    }
}

// ---------------------------------------------------------------------------
extern "C" void kernel_launch(void* const* d_in, const int* in_sizes, int n_in,
                              void* d_out, int out_size, void* d_ws, size_t ws_size,
                              hipStream_t stream)
{
    const float* x     = (const float*)d_in[0];
    const float* W_in  = (const float*)d_in[1];
    const float* cw    = (const float*)d_in[2];
    const float* cb    = (const float*)d_in[3];
    const float* W_g   = (const float*)d_in[4];
    const float* b_g   = (const float*)d_in[5];
    const float* fb    = (const float*)d_in[6];
    const float* W_out = (const float*)d_in[7];
    float* out = (float*)d_out;

    const size_t n_gi  = (size_t)BTC * 4096;            // bf16
    const size_t n_g   = (size_t)BTC * 4096;            // bf16
    const size_t n_xc  = (size_t)BTC * 2048;            // bf16
    const size_t n_sum = (size_t)NCHUNK * BBC * HIDC;   // float2 / float
    const size_t nX    = (size_t)BTC * DIMC;
    const size_t nWin  = (size_t)4096 * 1024;
    const size_t nWg   = (size_t)4096 * 2048;
    const size_t nWout = (size_t)1024 * 2048;

    const size_t need_base = (n_gi + n_g + n_xc) * 2 + n_sum * 12;     // 166 MiB
    const size_t need_full = need_base + (nWg + nWout) * 2;            // 186 MiB
    if (ws_size < need_base) return;
    const bool use8 = (ws_size >= need_full);

    unsigned short* gi = (unsigned short*)d_ws;
    unsigned short* g  = gi + n_gi;
    unsigned short* xc = g + n_g;
    float2* sums  = (float2*)(xc + n_xc);
    float*  carry = (float*)(sums + n_sum);
    unsigned short* wg_bf   = (unsigned short*)(carry + n_sum);
    unsigned short* wout_bf = wg_bf + nWg;
    unsigned short* x_bf   = g;            // aliases g (dead until GEMM2)
    unsigned short* win_bf = g + nX;

    if (use8) {
        const int n0 = (int)(nX / 8), n1 = (int)(nWin / 8),
                  n2 = (int)(nWg / 8), n3 = (int)(nWout / 8);
        cvt_all<<<(n0 + n1 + n2 + n3 + 255) / 256, 256, 0, stream>>>(
            x, x_bf, n0, W_in, win_bf, n1, W_g, wg_bf, n2, W_out, wout_bf, n3);

        // GEMM1: gi = x @ W_in^T        M=8192 N=4096 K=1024   nwg=512
        gemm8x<unsigned short, 0><<<512, 512, 0, stream>>>(
            x_bf, DIMC, win_bf, DIMC, gi, 4096, nullptr, DIMC, 16, 64);

        conv_k<<<(BTC * 512) / 256, 256, 0, stream>>>(gi, cw, cb, xc);

        // GEMM2: g = xc @ W_g^T + b_g   M=8192 N=4096 K=2048   nwg=512
        gemm8x<unsigned short, 1><<<512, 512, 0, stream>>>(
            xc, HIDC, wg_bf, HIDC, g, 4096, b_g, HIDC, 16, 64);

        scan1<<<(BBC * NCHUNK * HIDC) / 256, 256, 0, stream>>>(g, xc, fb, sums);
        scan2<<<(BBC * HIDC) / 256, 256, 0, stream>>>(sums, carry);
        scan3<<<(BBC * NCHUNK * HIDC) / 256, 256, 0, stream>>>(gi, g, xc, fb, carry);

        // GEMM3: out = u @ W_out^T      M=8192 N=1024 K=2048   gemm128 512 blocks
        gemm128<float><<<512, 256, 0, stream>>>(
            gi, 4096, wout_bf, HIDC, out, DIMC, HIDC, 8, 64);
    } else {
        gemm_bt<float, float, unsigned short, 0>
            <<<dim3(4096 / 128, BTC / 128), 256, 0, stream>>>(
            x, DIMC, W_in, DIMC, gi, 4096, nullptr, DIMC);
        conv_k<<<(BTC * 512) / 256, 256, 0, stream>>>(gi, cw, cb, xc);
        gemm_bt<unsigned short, float, unsigned short, 1>
            <<<dim3(4096 / 128, BTC / 128), 256, 0, stream>>>(
            xc, HIDC, W_g, HIDC, g, 4096, b_g, HIDC);
        scan1<<<(BBC * NCHUNK * HIDC) / 256, 256, 0, stream>>>(g, xc, fb, sums);
        scan2<<<(BBC * HIDC) / 256, 256, 0, stream>>>(sums, carry);
        scan3<<<(BBC * NCHUNK * HIDC) / 256, 256, 0, stream>>>(gi, g, xc, fb, carry);
        gemm_bt<unsigned short, float, float, 0>
            <<<dim3(DIMC / 128, BTC / 128), 256, 0, stream>>>(
            gi, 4096, W_out, HIDC, out, DIMC, nullptr, HIDC);
    }
}